// Round 1
// baseline (2080.245 us; speedup 1.0000x reference)
//
#include <hip/hip_runtime.h>
#include <math.h>

// LineFinderLoss: B=384 independent Jonker-Volgenant LSAs (L x 256, L<=64)
// + loss reduction. One wave (64 lanes) per batch; each lane owns 4 columns.
// Cost matrix replicated in fp32 exactly as numpy computes it; JV duals in
// fp64 exactly as the reference (_lsa casts cost to float64).

#define B_ 384
#define N_ 256
#define M_ 64

__global__ __launch_bounds__(64) void lsa_loss_kernel(
    const float* __restrict__ pred,
    const float* __restrict__ label,
    const int* __restrict__ label_len,
    double* __restrict__ ws)
{
  const int b = blockIdx.x;
  const int lane = threadIdx.x;  // 0..63

  __shared__ float lab_x[M_], lab_y[M_], lab_z[M_];
  __shared__ double u_lds[M_];
  __shared__ double shortest_lds[N_];
  __shared__ int prev_lds[N_];
  __shared__ int row4col[N_];   // pred column -> assigned label row (or -1)
  __shared__ int col4row[M_];   // label row  -> assigned pred column (or -1)

  // Load labels: one row per lane.
  {
    const float* lp = label + (size_t)(b * M_ + lane) * 3;
    lab_x[lane] = lp[0];
    lab_y[lane] = lp[1];
    lab_z[lane] = lp[2];
    u_lds[lane] = 0.0;
    col4row[lane] = -1;
  }

  // Per-lane column data (columns j = lane + 64k).
  float px[4], py[4], pz[4], lc[4], lca[4];
  double v[4];
  const float4* pred4 = reinterpret_cast<const float4*>(pred);
#pragma unroll
  for (int k = 0; k < 4; ++k) {
    const int j = lane + 64 * k;
    const float4 p = pred4[b * N_ + j];
    px[k] = p.x; py[k] = p.y; pz[k] = p.z;
    // numpy: log(conf + 1e-5), log(1 - conf + 1e-5), all fp32.
    lc[k]  = logf(__fadd_rn(p.w, 1e-5f));
    lca[k] = logf(__fadd_rn(__fsub_rn(1.0f, p.w), 1e-5f));
    v[k] = 0.0;
    row4col[j] = -1;
  }

  int L = label_len[b];
  L = (L < 1) ? 1 : ((L > M_) ? M_ : L);

  __syncthreads();

  const double INF = (double)INFINITY;

  for (int cur_row = 0; cur_row < L; ++cur_row) {
    double sh[4];
    bool sc[4];
#pragma unroll
    for (int k = 0; k < 4; ++k) { sh[k] = INF; sc[k] = false; }
    unsigned long long sr_mask = 0ull;
    double min_val = 0.0;
    int i = cur_row;
    int sink = -1;

    // Dijkstra shortest augmenting path; no barriers (single wave,
    // cross-lane state only touched at per-augment sync points).
    while (true) {
      sr_mask |= (1ull << i);
      const double u_i = u_lds[i];
      const float lx = lab_x[i], ly = lab_y[i], lz = lab_z[i];
#pragma unroll
      for (int k = 0; k < 4; ++k) {
        if (!sc[k]) {
          const int j = lane + 64 * k;
          // cost(i,j) in fp32, numpy association order, no FMA contraction:
          // C = ((0.1f*nd)/2 - log_c) + log_ca, nd = ((d0^2+d1^2)+d2^2)
          const float d0 = __fsub_rn(px[k], lx);
          const float d1 = __fsub_rn(py[k], ly);
          const float d2 = __fsub_rn(pz[k], lz);
          const float nd = __fadd_rn(__fadd_rn(__fmul_rn(d0, d0), __fmul_rn(d1, d1)),
                                     __fmul_rn(d2, d2));
          const float cf = __fadd_rn(__fsub_rn(__fdiv_rn(__fmul_rn(0.1f, nd), 2.0f), lc[k]),
                                     lca[k]);
          // fp64, exact reference order: ((min_val + c) - u[i]) - v[j]
          const double d = ((min_val + (double)cf) - u_i) - v[k];
          if (d < sh[k]) {
            sh[k] = d;
            shortest_lds[j] = d;  // write-through for dual update
            prev_lds[j] = i;
          }
        }
      }
      // argmin over non-SC columns; numpy tie-break = first (smallest) index.
      double m = INF;
      int mi = 0x7fffffff;
#pragma unroll
      for (int k = 0; k < 4; ++k) {
        const double vv = sc[k] ? INF : sh[k];
        if (vv < m) { m = vv; mi = lane + 64 * k; }  // ascending j: strict <
      }
      for (int off = 32; off >= 1; off >>= 1) {
        const double om = __shfl_xor(m, off, 64);
        const int omi = __shfl_xor(mi, off, 64);
        if (om < m || (om == m && omi < mi)) { m = om; mi = omi; }
      }
      min_val = m;
      const int j_min = mi;
      if ((j_min & 63) == lane) sc[j_min >> 6] = true;
      const int r4 = row4col[j_min];  // uniform broadcast read
      if (r4 < 0) { sink = j_min; break; }
      i = r4;
    }

    __syncthreads();  // shortest_lds / prev_lds visible to all lanes

    // Dual updates (must use pre-augmentation col4row).
    if ((sr_mask >> lane) & 1ull) {
      if (lane == cur_row) {
        u_lds[lane] += min_val;
      } else {
        u_lds[lane] += min_val - shortest_lds[col4row[lane]];
      }
    }
#pragma unroll
    for (int k = 0; k < 4; ++k) {
      if (sc[k]) v[k] -= (min_val - sh[k]);
    }

    __syncthreads();  // duals done before augmentation rewrites col4row

    if (lane == 0) {
      int j = sink;
      while (true) {
        const int ii = prev_lds[j];
        row4col[j] = ii;
        const int jn = col4row[ii];
        col4row[ii] = j;
        j = jn;
        if (ii == cur_row) break;
      }
    }
    __syncthreads();
  }

  // Per-batch loss partials.
  double loc = 0.0, cpos = 0.0, cneg = 0.0;
#pragma unroll
  for (int k = 0; k < 4; ++k) {
    const int j = lane + 64 * k;
    const int l = row4col[j];
    if (l >= 0) {
      const float d0 = __fsub_rn(px[k], lab_x[l]);
      const float d1 = __fsub_rn(py[k], lab_y[l]);
      const float d2 = __fsub_rn(pz[k], lab_z[l]);
      const float nd = __fadd_rn(__fadd_rn(__fmul_rn(d0, d0), __fmul_rn(d1, d1)),
                                 __fmul_rn(d2, d2));
      loc += (double)nd;
      cpos -= (double)lc[k];
    } else {
      cneg -= (double)lca[k];
    }
  }
  for (int off = 32; off >= 1; off >>= 1) {
    loc += __shfl_xor(loc, off, 64);
    cpos += __shfl_xor(cpos, off, 64);
    cneg += __shfl_xor(cneg, off, 64);
  }
  if (lane == 0) {
    ws[b * 3 + 0] = loc;   // sum of nd over matched pairs
    ws[b * 3 + 1] = cpos;  // -sum log_c over matched preds
    ws[b * 3 + 2] = cneg;  // -sum log_ca over unmatched preds
  }
}

__global__ __launch_bounds__(64) void reduce_kernel(
    const double* __restrict__ ws, float* __restrict__ out)
{
  const int lane = threadIdx.x;
  double loc = 0.0, conf = 0.0;
  for (int b = lane; b < B_; b += 64) {
    loc += ws[b * 3 + 0];
    conf += ws[b * 3 + 1] + ws[b * 3 + 2] + 1e-4;
  }
  for (int off = 32; off >= 1; off >>= 1) {
    loc += __shfl_xor(loc, off, 64);
    conf += __shfl_xor(conf, off, 64);
  }
  if (lane == 0) {
    const double location_loss = loc * 0.5;
    const double lloc = 0.1 * location_loss;          // ALPHA * location_loss
    out[0] = (float)(lloc + conf);                    // total loss
    out[1] = (float)lloc;                             // ALPHA * location_loss
    out[2] = (float)ws[(B_ - 1) * 3 + 1];             // conf_pos_b[-1]
    out[3] = (float)ws[(B_ - 1) * 3 + 2];             // conf_neg_b[-1]
  }
}

extern "C" void kernel_launch(void* const* d_in, const int* in_sizes, int n_in,
                              void* d_out, int out_size, void* d_ws, size_t ws_size,
                              hipStream_t stream) {
  const float* pred = (const float*)d_in[0];       // (B, N, 4) fp32
  const float* label = (const float*)d_in[1];      // (B, M, 3) fp32
  const int* label_len = (const int*)d_in[2];      // (B,) int32
  double* ws = (double*)d_ws;                      // B*3 doubles
  float* out = (float*)d_out;                      // 4 fp32 scalars

  lsa_loss_kernel<<<B_, 64, 0, stream>>>(pred, label, label_len, ws);
  reduce_kernel<<<1, 64, 0, stream>>>(ws, out);
}

// Round 2
// 1467.415 us; speedup vs baseline: 1.4176x; 1.4176x over previous
//
#include <hip/hip_runtime.h>
#include <math.h>

// LineFinderLoss: B=384 independent Jonker-Volgenant LSAs (L x 256, L<=64)
// + loss reduction. One wave per batch; each lane owns 4 columns.
// Round 2: hot Dijkstra loop is register/DPP-only —
//  - argmin via DPP reduce-to-lane63 (VALU latency) instead of ds_bpermute
//  - row4col of the argmin column carried in the argmin payload (aux)
//  - u[] and labels distributed per-lane, fetched via v_readlane (uniform idx)
// fp32 cost arithmetic and fp64 dual arithmetic keep the exact reference
// association order, so assignment decisions are bit-identical to numpy.

#define B_ 384
#define N_ 256
#define M_ 64

static __device__ __forceinline__ int lo32(double d) {
  return (int)__double_as_longlong(d);
}
static __device__ __forceinline__ int hi32(double d) {
  return (int)(__double_as_longlong(d) >> 32);
}
static __device__ __forceinline__ double mkdbl(int lo, int hi) {
  return __longlong_as_double(((long long)hi << 32) | (unsigned int)lo);
}
static __device__ __forceinline__ double readlane_f64(double x, int l) {
  int lo = __builtin_amdgcn_readlane(lo32(x), l);
  int hi = __builtin_amdgcn_readlane(hi32(x), l);
  return mkdbl(lo, hi);
}
static __device__ __forceinline__ float readlane_f32(float x, int l) {
  return __int_as_float(__builtin_amdgcn_readlane(__float_as_int(x), l));
}

// Lexicographic-min reduce step over (double cv, int ca) via DPP.
// Invalid/masked lanes contribute (+inf, INT_MAX) via the `old` operand.
#define DPP_MIN_STEP(CTRL, RMASK)                                              \
  {                                                                            \
    int nlo = __builtin_amdgcn_update_dpp(0, lo32(cv), CTRL, RMASK, 0xF, false);          \
    int nhi = __builtin_amdgcn_update_dpp(0x7FF00000, hi32(cv), CTRL, RMASK, 0xF, false); \
    int na  = __builtin_amdgcn_update_dpp(0x7FFFFFFF, ca, CTRL, RMASK, 0xF, false);       \
    double nv = mkdbl(nlo, nhi);                                               \
    bool take = (nv < cv) || (nv == cv && na < ca);                            \
    cv = take ? nv : cv;                                                       \
    ca = take ? na : ca;                                                       \
  }

__global__ __launch_bounds__(64) void lsa_loss_kernel(
    const float* __restrict__ pred,
    const float* __restrict__ label,
    const int* __restrict__ label_len,
    double* __restrict__ ws)
{
  const int b = blockIdx.x;
  const int lane = threadIdx.x;  // 0..63

  __shared__ float lab_x[M_], lab_y[M_], lab_z[M_];
  __shared__ double shortest_lds[N_];
  __shared__ int prev_lds[N_];
  __shared__ int row4col[N_];   // pred column -> assigned label row (or -1)
  __shared__ int col4row[M_];   // label row  -> assigned pred column (or -1)

  // Labels: lane r owns label row r (registers) + LDS copy for the epilogue.
  const float* lp = label + (size_t)(b * M_ + lane) * 3;
  const float labx = lp[0], laby = lp[1], labz = lp[2];
  lab_x[lane] = labx; lab_y[lane] = laby; lab_z[lane] = labz;
  col4row[lane] = -1;
  double u_reg = 0.0;  // u[lane]

  // Per-lane column data (columns j = lane + 64k).
  float px[4], py[4], pz[4], lc[4], lca[4];
  double v[4];
  int ba[4];  // argmin payload per column: (j << 9) | (row4col[j] + 1)
  const float4* pred4 = reinterpret_cast<const float4*>(pred);
#pragma unroll
  for (int k = 0; k < 4; ++k) {
    const int j = lane + 64 * k;
    const float4 p = pred4[b * N_ + j];
    px[k] = p.x; py[k] = p.y; pz[k] = p.z;
    lc[k]  = logf(__fadd_rn(p.w, 1e-5f));
    lca[k] = logf(__fadd_rn(__fsub_rn(1.0f, p.w), 1e-5f));
    v[k] = 0.0;
    row4col[j] = -1;
    ba[k] = (j << 9);  // rc = -1  ->  rc+1 = 0
  }

  int L = label_len[b];
  L = (L < 1) ? 1 : ((L > M_) ? M_ : L);

  __syncthreads();

  const double INF = (double)INFINITY;

  for (int cur_row = 0; cur_row < L; ++cur_row) {
    double sh[4] = {INF, INF, INF, INF};
    unsigned scmask = 0;
    unsigned long long sr_mask = 0ull;
    double min_val = 0.0;
    int i_cur = cur_row;
    double u_i = readlane_f64(u_reg, i_cur);
    float lx = readlane_f32(labx, i_cur);
    float ly = readlane_f32(laby, i_cur);
    float lz = readlane_f32(labz, i_cur);
    int sink = -1;

    while (true) {
      sr_mask |= (1ull << i_cur);
#pragma unroll
      for (int k = 0; k < 4; ++k) {
        // cost(i,j) in fp32, numpy association order, no FMA contraction.
        const float d0 = __fsub_rn(px[k], lx);
        const float d1 = __fsub_rn(py[k], ly);
        const float d2 = __fsub_rn(pz[k], lz);
        const float nd = __fadd_rn(__fadd_rn(__fmul_rn(d0, d0), __fmul_rn(d1, d1)),
                                   __fmul_rn(d2, d2));
        // (0.1f*nd)/2.0f == (0.1f*nd)*0.5f bit-exactly (binary scaling).
        const float cf = __fadd_rn(__fsub_rn(__fmul_rn(__fmul_rn(0.1f, nd), 0.5f), lc[k]),
                                   lca[k]);
        // fp64, exact reference order: ((min_val + c) - u[i]) - v[j]
        const double dd = ((min_val + (double)cf) - u_i) - v[k];
        const bool upd = (dd < sh[k]) && !((scmask >> k) & 1u);
        if (upd) {
          sh[k] = dd;
          const int j = lane + 64 * k;
          shortest_lds[j] = dd;   // write-through for the dual update
          prev_lds[j] = i_cur;
        }
      }
      // Per-lane candidate: strict < over ascending j gives first-index ties.
      double cv = INF; int ca = 0x7FFFFFFF;
#pragma unroll
      for (int k = 0; k < 4; ++k) {
        const bool c = (!((scmask >> k) & 1u)) && (sh[k] < cv);
        cv = c ? sh[k] : cv;
        ca = c ? ba[k] : ca;
      }
      // Wave min-reduce into lane 63 (j in aux high bits => first-index ties).
      DPP_MIN_STEP(0x111, 0xF);  // row_shr:1
      DPP_MIN_STEP(0x112, 0xF);  // row_shr:2
      DPP_MIN_STEP(0x114, 0xF);  // row_shr:4
      DPP_MIN_STEP(0x118, 0xF);  // row_shr:8
      DPP_MIN_STEP(0x142, 0xA);  // row_bcast:15 -> rows 1,3
      DPP_MIN_STEP(0x143, 0xC);  // row_bcast:31 -> rows 2,3
      min_val = readlane_f64(cv, 63);
      const int aux = __builtin_amdgcn_readlane(ca, 63);
      const int j_min = aux >> 9;
      if (lane == (j_min & 63)) scmask |= (1u << (j_min >> 6));
      const int r4 = (aux & 0x1FF) - 1;  // row4col[j_min], carried in payload
      if (r4 < 0) { sink = j_min; break; }
      i_cur = r4;
      u_i = readlane_f64(u_reg, i_cur);
      lx = readlane_f32(labx, i_cur);
      ly = readlane_f32(laby, i_cur);
      lz = readlane_f32(labz, i_cur);
    }

    __syncthreads();  // shortest_lds / prev_lds visible to all lanes

    // Dual updates (pre-augmentation col4row).
    if ((sr_mask >> lane) & 1ull) {
      if (lane == cur_row) u_reg += min_val;
      else                 u_reg += min_val - shortest_lds[col4row[lane]];
    }
#pragma unroll
    for (int k = 0; k < 4; ++k) {
      if ((scmask >> k) & 1u) v[k] -= (min_val - sh[k]);
    }

    __syncthreads();  // duals done before augmentation rewrites col4row

    if (lane == 0) {
      int j = sink;
      while (true) {
        const int ii = prev_lds[j];
        row4col[j] = ii;
        const int jn = col4row[ii];
        col4row[ii] = j;
        j = jn;
        if (ii == cur_row) break;
      }
    }
    __syncthreads();

    // Refresh argmin payloads with the new row4col.
#pragma unroll
    for (int k = 0; k < 4; ++k) {
      const int j = lane + 64 * k;
      ba[k] = (j << 9) | (row4col[j] + 1);
    }
  }

  // Per-batch loss partials.
  double loc = 0.0, cpos = 0.0, cneg = 0.0;
#pragma unroll
  for (int k = 0; k < 4; ++k) {
    const int j = lane + 64 * k;
    const int l = row4col[j];
    if (l >= 0) {
      const float d0 = __fsub_rn(px[k], lab_x[l]);
      const float d1 = __fsub_rn(py[k], lab_y[l]);
      const float d2 = __fsub_rn(pz[k], lab_z[l]);
      const float nd = __fadd_rn(__fadd_rn(__fmul_rn(d0, d0), __fmul_rn(d1, d1)),
                                 __fmul_rn(d2, d2));
      loc += (double)nd;
      cpos -= (double)lc[k];
    } else {
      cneg -= (double)lca[k];
    }
  }
  for (int off = 32; off >= 1; off >>= 1) {
    loc += __shfl_xor(loc, off, 64);
    cpos += __shfl_xor(cpos, off, 64);
    cneg += __shfl_xor(cneg, off, 64);
  }
  if (lane == 0) {
    ws[b * 3 + 0] = loc;   // sum of nd over matched pairs
    ws[b * 3 + 1] = cpos;  // -sum log_c over matched preds
    ws[b * 3 + 2] = cneg;  // -sum log_ca over unmatched preds
  }
}

__global__ __launch_bounds__(64) void reduce_kernel(
    const double* __restrict__ ws, float* __restrict__ out)
{
  const int lane = threadIdx.x;
  double loc = 0.0, conf = 0.0;
  for (int b = lane; b < B_; b += 64) {
    loc += ws[b * 3 + 0];
    conf += ws[b * 3 + 1] + ws[b * 3 + 2] + 1e-4;
  }
  for (int off = 32; off >= 1; off >>= 1) {
    loc += __shfl_xor(loc, off, 64);
    conf += __shfl_xor(conf, off, 64);
  }
  if (lane == 0) {
    const double location_loss = loc * 0.5;
    const double lloc = 0.1 * location_loss;          // ALPHA * location_loss
    out[0] = (float)(lloc + conf);                    // total loss
    out[1] = (float)lloc;                             // ALPHA * location_loss
    out[2] = (float)ws[(B_ - 1) * 3 + 1];             // conf_pos_b[-1]
    out[3] = (float)ws[(B_ - 1) * 3 + 2];             // conf_neg_b[-1]
  }
}

extern "C" void kernel_launch(void* const* d_in, const int* in_sizes, int n_in,
                              void* d_out, int out_size, void* d_ws, size_t ws_size,
                              hipStream_t stream) {
  const float* pred = (const float*)d_in[0];       // (B, N, 4) fp32
  const float* label = (const float*)d_in[1];      // (B, M, 3) fp32
  const int* label_len = (const int*)d_in[2];      // (B,) int32
  double* ws = (double*)d_ws;                      // B*3 doubles
  float* out = (float*)d_out;                      // 4 fp32 scalars

  lsa_loss_kernel<<<B_, 64, 0, stream>>>(pred, label, label_len, ws);
  reduce_kernel<<<1, 64, 0, stream>>>(ws, out);
}

// Round 4
// 1300.402 us; speedup vs baseline: 1.5997x; 1.1284x over previous
//
#include <hip/hip_runtime.h>
#include <math.h>

// LineFinderLoss: B=384 independent exact LSAs (L x 256, L<=64) + loss.
// One wave per batch; each lane owns 4 pred columns (j = lane + 64k).
// Round 4: revert invalid column-reduction warm start (R3 bug: rectangular
// duals need v<=0 and v=0 on unmatched columns). Instead:
//  - VALID row-reduction warm start: u_i = min_j C_ij, v = 0, greedy claim
//    of each row's argmin column (tight edges, feasible duals) -> exact SSP.
//  - u64-key Dijkstra: d >= 0 so bits(f64 d) are u64-monotone. Pack
//    key = (bits(d) & ~0x7FFF) | (j << 7) | (row4col[j]+1). Selection,
//    tie-break (first j), row4col lookup, min_val all come from ONE u64 min.
//    15-bit mantissa truncation perturbs d by ~2^-37 rel (loss-safe).

#define B_ 384
#define N_ 256
#define M_ 64

typedef unsigned long long u64;
#define KEYMASK 0xFFFFFFFFFFFF8000ull

static __device__ __forceinline__ double readlane_f64(double x, int l) {
  long long bl = __double_as_longlong(x);
  int lo = __builtin_amdgcn_readlane((int)bl, l);
  int hi = __builtin_amdgcn_readlane((int)(bl >> 32), l);
  return __longlong_as_double(((long long)hi << 32) | (unsigned int)lo);
}
static __device__ __forceinline__ float readlane_f32(float x, int l) {
  return __int_as_float(__builtin_amdgcn_readlane(__float_as_int(x), l));
}
static __device__ __forceinline__ u64 readlane_u64(u64 x, int l) {
  int lo = __builtin_amdgcn_readlane((int)x, l);
  int hi = __builtin_amdgcn_readlane((int)(x >> 32), l);
  return ((u64)(unsigned int)hi << 32) | (unsigned int)lo;
}

// fp32 cost with numpy's exact association order (bit-exact vs reference):
// C = ((0.1f*nd)*0.5f - lc) + lca, nd = (d0*d0 + d1*d1) + d2*d2
static __device__ __forceinline__ float costf(float px, float py, float pz,
                                              float lc, float lca,
                                              float lx, float ly, float lz) {
  const float d0 = __fsub_rn(px, lx);
  const float d1 = __fsub_rn(py, ly);
  const float d2 = __fsub_rn(pz, lz);
  const float nd = __fadd_rn(__fadd_rn(__fmul_rn(d0, d0), __fmul_rn(d1, d1)),
                             __fmul_rn(d2, d2));
  return __fadd_rn(__fsub_rn(__fmul_rn(__fmul_rn(0.1f, nd), 0.5f), lc), lca);
}

// u64 min-reduce step via DPP; disabled/masked lanes contribute UINT64_MAX.
#define DPP_MIN_U64(CTRL, RMASK)                                               \
  {                                                                            \
    int nlo = __builtin_amdgcn_update_dpp(-1, (int)ck, CTRL, RMASK, 0xF, false);        \
    int nhi = __builtin_amdgcn_update_dpp(-1, (int)(ck >> 32), CTRL, RMASK, 0xF, false);\
    u64 nk = ((u64)(unsigned int)nhi << 32) | (unsigned int)nlo;               \
    ck = (nk < ck) ? nk : ck;                                                  \
  }

__global__ __launch_bounds__(64) void lsa_loss_kernel(
    const float* __restrict__ pred,
    const float* __restrict__ label,
    const int* __restrict__ label_len,
    double* __restrict__ ws)
{
  const int b = blockIdx.x;
  const int lane = threadIdx.x;  // 0..63

  __shared__ float lab_x[M_], lab_y[M_], lab_z[M_];
  __shared__ double shortest_lds[N_];
  __shared__ int prev_lds[N_];
  __shared__ int row4col[N_];   // pred column -> assigned label row (or -1)
  __shared__ int col4row[M_];   // label row  -> assigned pred column (or -1)
  __shared__ int claim[N_];     // greedy: min row index claiming column j
  __shared__ float4 colA[N_];   // {px, py, pz, lc} per column
  __shared__ float collca[N_];

  // Labels: lane r owns label row r (registers) + LDS copy for the epilogue.
  const float* lp = label + (size_t)(b * M_ + lane) * 3;
  const float labx = lp[0], laby = lp[1], labz = lp[2];
  lab_x[lane] = labx; lab_y[lane] = laby; lab_z[lane] = labz;
  col4row[lane] = -1;

  // Per-lane column data.
  float px[4], py[4], pz[4], lc[4], lca[4];
  double v[4];
  int ba[4];  // key payload: (j << 7) | (row4col[j] + 1)
  const float4* pred4 = reinterpret_cast<const float4*>(pred);
#pragma unroll
  for (int k = 0; k < 4; ++k) {
    const int j = lane + 64 * k;
    const float4 p = pred4[b * N_ + j];
    px[k] = p.x; py[k] = p.y; pz[k] = p.z;
    lc[k]  = logf(__fadd_rn(p.w, 1e-5f));
    lca[k] = logf(__fadd_rn(__fsub_rn(1.0f, p.w), 1e-5f));
    v[k] = 0.0;
    row4col[j] = -1;
    claim[j] = 0x7FFFFFFF;
    colA[j] = make_float4(p.x, p.y, p.z, lc[k]);
    collca[j] = lca[k];
  }

  int L = label_len[b];
  L = (L < 1) ? 1 : ((L > M_) ? M_ : L);

  __syncthreads();

  // ---- VALID warm start: u_i = min_j C_ij (row reduction), v = 0 ----
  // Matched edge (i, argmin) has reduced cost exactly 0; v=0 satisfies the
  // rectangular dual constraint (v<=0, v=0 on unmatched columns).
  float uminf = INFINITY;
  int bj = 0;
#pragma unroll 4
  for (int j = 0; j < N_; ++j) {
    const float4 c4 = colA[j];     // broadcast (all lanes same addr)
    const float clca = collca[j];
    const float cf = costf(c4.x, c4.y, c4.z, c4.w, clca, labx, laby, labz);
    if (cf < uminf) { uminf = cf; bj = j; }  // strict <: first-index ties
  }
  double u_reg = (double)uminf;
  if (lane < L) atomicMin(&claim[bj], lane);
  __syncthreads();
  const bool won = (lane < L) && (claim[bj] == lane);
  if (won) { col4row[lane] = bj; row4col[bj] = lane; }
  u64 free_mask = __ballot((lane < L) && !won);
  __syncthreads();

#pragma unroll
  for (int k = 0; k < 4; ++k) {
    const int j = lane + 64 * k;
    ba[k] = (j << 7) | (row4col[j] + 1);
  }

  // ---- Augment free rows (ascending): exact shortest augmenting path ----
  while (free_mask) {
    const int cur_row = (int)__builtin_ctzll(free_mask);
    free_mask &= free_mask - 1;

    u64 shk[4]  = {~0ull, ~0ull, ~0ull, ~0ull};  // frozen at pop (v-duals)
    u64 cndk[4] = {~0ull, ~0ull, ~0ull, ~0ull};  // = shk, UINT64_MAX once SC
    unsigned scmask = 0;
    u64 sr_mask = 0ull;
    double min_val = 0.0;
    int i_cur = cur_row;
    double t = 0.0 - readlane_f64(u_reg, i_cur);  // t = min_val - u_i
    float lx = readlane_f32(labx, i_cur);
    float ly = readlane_f32(laby, i_cur);
    float lz = readlane_f32(labz, i_cur);
    int sink = -1;

    while (true) {
      sr_mask |= (1ull << i_cur);
#pragma unroll
      for (int k = 0; k < 4; ++k) {
        const float cf = costf(px[k], py[k], pz[k], lc[k], lca[k], lx, ly, lz);
        double dd = ((double)cf + t) - v[k];
        dd = fmax(dd, 0.0);  // guard vs -1ulp feasibility drift (key sign)
        const u64 key = ((u64)__double_as_longlong(dd) & KEYMASK) | (u64)ba[k];
        const bool upd = (key < shk[k]) && !((scmask >> k) & 1u);
        if (upd) {
          shk[k] = key; cndk[k] = key;
          const int j = lane + 64 * k;
          shortest_lds[j] = __longlong_as_double((long long)(key & KEYMASK));
          prev_lds[j] = i_cur;
        }
      }
      // Pure u64 min: key embeds (d, j, row4col[j]) with first-j tie-break.
      const u64 m01 = (cndk[0] < cndk[1]) ? cndk[0] : cndk[1];
      const u64 m23 = (cndk[2] < cndk[3]) ? cndk[2] : cndk[3];
      u64 ck = (m01 < m23) ? m01 : m23;
      DPP_MIN_U64(0x111, 0xF);  // row_shr:1
      DPP_MIN_U64(0x112, 0xF);  // row_shr:2
      DPP_MIN_U64(0x114, 0xF);  // row_shr:4
      DPP_MIN_U64(0x118, 0xF);  // row_shr:8
      DPP_MIN_U64(0x142, 0xA);  // row_bcast:15 -> rows 1,3
      DPP_MIN_U64(0x143, 0xC);  // row_bcast:31 -> rows 2,3
      const u64 wk = readlane_u64(ck, 63);
      min_val = __longlong_as_double((long long)(wk & KEYMASK));
      const int j_min = (int)((wk >> 7) & 0xFF);
      if (lane == (j_min & 63)) {
        const int kk = j_min >> 6;
        scmask |= (1u << kk);
        cndk[kk] = ~0ull;
      }
      const int r4 = (int)(wk & 0x7F) - 1;  // row4col[j_min] from payload
      if (r4 < 0) { sink = j_min; break; }
      i_cur = r4;
      t = min_val - readlane_f64(u_reg, i_cur);
      lx = readlane_f32(labx, i_cur);
      ly = readlane_f32(laby, i_cur);
      lz = readlane_f32(labz, i_cur);
    }

    __syncthreads();  // shortest_lds / prev_lds visible

    // Dual updates (pre-augmentation col4row), reference semantics.
    if ((sr_mask >> lane) & 1ull) {
      if (lane == cur_row) u_reg += min_val;
      else                 u_reg += min_val - shortest_lds[col4row[lane]];
    }
#pragma unroll
    for (int k = 0; k < 4; ++k) {
      if ((scmask >> k) & 1u) {
        const double shd = __longlong_as_double((long long)(shk[k] & KEYMASK));
        v[k] -= (min_val - shd);
      }
    }

    __syncthreads();  // duals done before augmentation rewrites col4row

    if (lane == 0) {
      int j = sink;
      while (true) {
        const int ii = prev_lds[j];
        row4col[j] = ii;
        const int jn = col4row[ii];
        col4row[ii] = j;
        j = jn;
        if (ii == cur_row) break;
      }
    }
    __syncthreads();

#pragma unroll
    for (int k = 0; k < 4; ++k) {
      const int j = lane + 64 * k;
      ba[k] = (j << 7) | (row4col[j] + 1);
    }
  }

  // ---- Per-batch loss partials (identical fp order to R1/R2) ----
  double loc = 0.0, cpos = 0.0, cneg = 0.0;
#pragma unroll
  for (int k = 0; k < 4; ++k) {
    const int j = lane + 64 * k;
    const int l = row4col[j];
    if (l >= 0) {
      const float d0 = __fsub_rn(px[k], lab_x[l]);
      const float d1 = __fsub_rn(py[k], lab_y[l]);
      const float d2 = __fsub_rn(pz[k], lab_z[l]);
      const float nd = __fadd_rn(__fadd_rn(__fmul_rn(d0, d0), __fmul_rn(d1, d1)),
                                 __fmul_rn(d2, d2));
      loc += (double)nd;
      cpos -= (double)lc[k];
    } else {
      cneg -= (double)lca[k];
    }
  }
  for (int off = 32; off >= 1; off >>= 1) {
    loc += __shfl_xor(loc, off, 64);
    cpos += __shfl_xor(cpos, off, 64);
    cneg += __shfl_xor(cneg, off, 64);
  }
  if (lane == 0) {
    ws[b * 3 + 0] = loc;   // sum of nd over matched pairs
    ws[b * 3 + 1] = cpos;  // -sum log_c over matched preds
    ws[b * 3 + 2] = cneg;  // -sum log_ca over unmatched preds
  }
}

__global__ __launch_bounds__(64) void reduce_kernel(
    const double* __restrict__ ws, float* __restrict__ out)
{
  const int lane = threadIdx.x;
  double loc = 0.0, conf = 0.0;
  for (int b = lane; b < B_; b += 64) {
    loc += ws[b * 3 + 0];
    conf += ws[b * 3 + 1] + ws[b * 3 + 2] + 1e-4;
  }
  for (int off = 32; off >= 1; off >>= 1) {
    loc += __shfl_xor(loc, off, 64);
    conf += __shfl_xor(conf, off, 64);
  }
  if (lane == 0) {
    const double location_loss = loc * 0.5;
    const double lloc = 0.1 * location_loss;          // ALPHA * location_loss
    out[0] = (float)(lloc + conf);                    // total loss
    out[1] = (float)lloc;                             // ALPHA * location_loss
    out[2] = (float)ws[(B_ - 1) * 3 + 1];             // conf_pos_b[-1]
    out[3] = (float)ws[(B_ - 1) * 3 + 2];             // conf_neg_b[-1]
  }
}

extern "C" void kernel_launch(void* const* d_in, const int* in_sizes, int n_in,
                              void* d_out, int out_size, void* d_ws, size_t ws_size,
                              hipStream_t stream) {
  const float* pred = (const float*)d_in[0];       // (B, N, 4) fp32
  const float* label = (const float*)d_in[1];      // (B, M, 3) fp32
  const int* label_len = (const int*)d_in[2];      // (B,) int32
  double* ws = (double*)d_ws;                      // B*3 doubles
  float* out = (float*)d_out;                      // 4 fp32 scalars

  lsa_loss_kernel<<<B_, 64, 0, stream>>>(pred, label, label_len, ws);
  reduce_kernel<<<1, 64, 0, stream>>>(ws, out);
}

// Round 5
// 571.499 us; speedup vs baseline: 3.6400x; 2.2754x over previous
//
#include <hip/hip_runtime.h>
#include <math.h>

// LineFinderLoss: B=384 independent exact LSAs (L x 256, L<=64) + loss.
// One wave per batch; each lane owns 4 pred columns (j = lane + 64k).
// Round 5: per-pop critical-path cut. Keys are non-negative doubles with an
// 8-bit column payload in the mantissa LSBs (f64 order == u64 order), so the
// wave argmin is a pure v_min_f64 DPP chain. row4col is carried in registers
// (static during a Dijkstra) and fetched by readlane, not in the key.
// SC columns are masked to a HUGE-FINITE value (no NaN semantics risk).
// Same compare semantics as R4 (absmax 0), truncation now 2^-44 rel.

#define B_ 384
#define N_ 256
#define M_ 64

typedef unsigned long long u64;

static __device__ __forceinline__ double mkdbl(int lo, int hi) {
  return __longlong_as_double(((long long)hi << 32) | (unsigned int)lo);
}
static __device__ __forceinline__ int lo32d(double d) {
  return (int)__double_as_longlong(d);
}
static __device__ __forceinline__ int hi32d(double d) {
  return (int)(__double_as_longlong(d) >> 32);
}
static __device__ __forceinline__ float readlane_f32(float x, int l) {
  return __int_as_float(__builtin_amdgcn_readlane(__float_as_int(x), l));
}
static __device__ __forceinline__ double readlane_f64(double x, int l) {
  int lo = __builtin_amdgcn_readlane(lo32d(x), l);
  int hi = __builtin_amdgcn_readlane(hi32d(x), l);
  return mkdbl(lo, hi);
}

// fp32 cost with numpy's exact association order (bit-exact vs reference):
// C = ((0.1f*nd)*0.5f - lc) + lca, nd = (d0*d0 + d1*d1) + d2*d2
static __device__ __forceinline__ float costf(float px, float py, float pz,
                                              float lc, float lca,
                                              float lx, float ly, float lz) {
  const float d0 = __fsub_rn(px, lx);
  const float d1 = __fsub_rn(py, ly);
  const float d2 = __fsub_rn(pz, lz);
  const float nd = __fadd_rn(__fadd_rn(__fmul_rn(d0, d0), __fmul_rn(d1, d1)),
                             __fmul_rn(d2, d2));
  return __fadd_rn(__fsub_rn(__fmul_rn(__fmul_rn(0.1f, nd), 0.5f), lc), lca);
}

// f64 min-reduce step via DPP (keys are finite, >= 0, payload in low byte).
// Lanes without a source get max-finite-double (lo=-1, hi=0x7FEFFFFF).
#define DPP_MIN_F64(CTRL, RMASK)                                               \
  {                                                                            \
    int nlo = __builtin_amdgcn_update_dpp(-1, lo32d(ck), CTRL, RMASK, 0xF, false);         \
    int nhi = __builtin_amdgcn_update_dpp(0x7FEFFFFF, hi32d(ck), CTRL, RMASK, 0xF, false); \
    ck = fmin(ck, mkdbl(nlo, nhi));                                            \
  }

__global__ __launch_bounds__(64) void lsa_loss_kernel(
    const float* __restrict__ pred,
    const float* __restrict__ label,
    const int* __restrict__ label_len,
    double* __restrict__ ws)
{
  const int b = blockIdx.x;
  const int lane = threadIdx.x;  // 0..63

  __shared__ float lab_x[M_], lab_y[M_], lab_z[M_];
  __shared__ double shortest_lds[N_];
  __shared__ int prev_lds[N_];
  __shared__ int row4col[N_];   // pred column -> assigned label row (or -1)
  __shared__ int col4row[M_];   // label row  -> assigned pred column (or -1)
  __shared__ int claim[N_];     // greedy: min row index claiming column j
  __shared__ float4 colA[N_];   // {px, py, pz, lc} per column
  __shared__ float collca[N_];

  // Labels: lane r owns label row r (registers) + LDS copy for the epilogue.
  const float* lp = label + (size_t)(b * M_ + lane) * 3;
  const float labx = lp[0], laby = lp[1], labz = lp[2];
  lab_x[lane] = labx; lab_y[lane] = laby; lab_z[lane] = labz;
  col4row[lane] = -1;

  // Per-lane column data.
  float px[4], py[4], pz[4], lc[4], lca[4];
  double v[4];
  const float4* pred4 = reinterpret_cast<const float4*>(pred);
#pragma unroll
  for (int k = 0; k < 4; ++k) {
    const int j = lane + 64 * k;
    const float4 p = pred4[b * N_ + j];
    px[k] = p.x; py[k] = p.y; pz[k] = p.z;
    lc[k]  = logf(__fadd_rn(p.w, 1e-5f));
    lca[k] = logf(__fadd_rn(__fsub_rn(1.0f, p.w), 1e-5f));
    v[k] = 0.0;
    row4col[j] = -1;
    claim[j] = 0x7FFFFFFF;
    colA[j] = make_float4(p.x, p.y, p.z, lc[k]);
    collca[j] = lca[k];
  }

  int L = label_len[b];
  L = (L < 1) ? 1 : ((L > M_) ? M_ : L);

  __syncthreads();

  // ---- VALID warm start: u_i = min_j C_ij (row reduction), v = 0 ----
  float uminf = INFINITY;
  int bj = 0;
#pragma unroll 4
  for (int j = 0; j < N_; ++j) {
    const float4 c4 = colA[j];     // broadcast (all lanes same addr)
    const float clca = collca[j];
    const float cf = costf(c4.x, c4.y, c4.z, c4.w, clca, labx, laby, labz);
    if (cf < uminf) { uminf = cf; bj = j; }  // strict <: first-index ties
  }
  double u_reg = (double)uminf;
  if (lane < L) atomicMin(&claim[bj], lane);
  __syncthreads();
  const bool won = (lane < L) && (claim[bj] == lane);
  if (won) { col4row[lane] = bj; row4col[bj] = lane; }
  u64 free_mask = __ballot((lane < L) && !won);
  __syncthreads();

  // row4col distributed in registers (static during each Dijkstra).
  int rfc[4];
#pragma unroll
  for (int k = 0; k < 4; ++k) rfc[k] = row4col[lane + 64 * k];

  const double INF = (double)INFINITY;

  // ---- Augment free rows (ascending): exact shortest augmenting path ----
  while (free_mask) {
    const int cur_row = (int)__builtin_ctzll(free_mask);
    free_mask &= free_mask - 1;

    double shk[4] = {INF, INF, INF, INF};  // key-doubles, frozen at pop
    int schi[4] = {0, 0, 0, 0};            // SC flag per owned column
    u64 sr_mask = 0ull;
    double min_val = 0.0;
    int i_cur = cur_row;
    double u_i = readlane_f64(u_reg, i_cur);
    float lx = readlane_f32(labx, i_cur);
    float ly = readlane_f32(laby, i_cur);
    float lz = readlane_f32(labz, i_cur);
    double t = 0.0 - u_i;  // t = min_val - u_i
    int sink = -1;

    while (true) {
      sr_mask |= (1ull << i_cur);
      double tv[4];
#pragma unroll
      for (int k = 0; k < 4; ++k) tv[k] = t - v[k];

      double cand[4];
#pragma unroll
      for (int k = 0; k < 4; ++k) {
        const int j = lane + 64 * k;
        const float cf = costf(px[k], py[k], pz[k], lc[k], lca[k], lx, ly, lz);
        double dd = (double)cf + tv[k];
        dd = fmax(dd, 0.0);  // keys stay >= 0 (sign-safe ordering)
        const int klo = (lo32d(dd) & ~0xFF) | j;   // j in [0,255] == low byte
        const int khi = hi32d(dd);
        // SC mask: hi word -> 0x7FEFFFFF gives a huge FINITE value (no NaN).
        const int khi_m = schi[k] ? 0x7FEFFFFF : khi;
        const double c = mkdbl(klo, khi_m);
        const bool upd = c < shk[k];
        if (upd) {
          shk[k] = c;
          shortest_lds[j] = mkdbl(klo & ~0xFF, khi);  // payload-stripped
          prev_lds[j] = i_cur;
        }
        cand[k] = c;
      }
      // 2-level tree + 6 DPP steps, all v_min_f64.
      const double m01 = fmin(cand[0], cand[1]);
      const double m23 = fmin(cand[2], cand[3]);
      double ck = fmin(m01, m23);
      DPP_MIN_F64(0x111, 0xF);  // row_shr:1
      DPP_MIN_F64(0x112, 0xF);  // row_shr:2
      DPP_MIN_F64(0x114, 0xF);  // row_shr:4
      DPP_MIN_F64(0x118, 0xF);  // row_shr:8
      DPP_MIN_F64(0x142, 0xA);  // row_bcast:15 -> rows 1,3
      DPP_MIN_F64(0x143, 0xC);  // row_bcast:31 -> rows 2,3
      const int wlo = __builtin_amdgcn_readlane(lo32d(ck), 63);
      const int whi = __builtin_amdgcn_readlane(hi32d(ck), 63);
      const int j_min = wlo & 0xFF;
      min_val = mkdbl(wlo & ~0xFF, whi);
      const int kk = j_min >> 6;
      // Branch-free SC mark (avoid dynamic register indexing).
      const int hit = (lane == (j_min & 63)) ? 1 : 0;
      schi[0] |= hit & (int)(kk == 0);
      schi[1] |= hit & (int)(kk == 1);
      schi[2] |= hit & (int)(kk == 2);
      schi[3] |= hit & (int)(kk == 3);
      // row4col[j_min] from distributed registers (static this Dijkstra).
      const int lsel = j_min & 63;
      const int r0 = __builtin_amdgcn_readlane(rfc[0], lsel);
      const int r1 = __builtin_amdgcn_readlane(rfc[1], lsel);
      const int r2 = __builtin_amdgcn_readlane(rfc[2], lsel);
      const int r3 = __builtin_amdgcn_readlane(rfc[3], lsel);
      const int r4 = (kk == 0) ? r0 : (kk == 1) ? r1 : (kk == 2) ? r2 : r3;
      if (r4 < 0) { sink = j_min; break; }
      i_cur = r4;
      u_i = readlane_f64(u_reg, i_cur);
      lx = readlane_f32(labx, i_cur);
      ly = readlane_f32(laby, i_cur);
      lz = readlane_f32(labz, i_cur);
      t = min_val - u_i;
    }

    __syncthreads();  // shortest_lds / prev_lds visible

    // Dual updates (pre-augmentation col4row), reference semantics.
    if ((sr_mask >> lane) & 1ull) {
      if (lane == cur_row) u_reg += min_val;
      else                 u_reg += min_val - shortest_lds[col4row[lane]];
    }
#pragma unroll
    for (int k = 0; k < 4; ++k) {
      if (schi[k]) {
        const double shd = mkdbl(lo32d(shk[k]) & ~0xFF, hi32d(shk[k]));
        v[k] -= (min_val - shd);
      }
    }

    __syncthreads();  // duals done before augmentation rewrites col4row

    if (lane == 0) {
      int j = sink;
      while (true) {
        const int ii = prev_lds[j];
        row4col[j] = ii;
        const int jn = col4row[ii];
        col4row[ii] = j;
        j = jn;
        if (ii == cur_row) break;
      }
    }
    __syncthreads();

#pragma unroll
    for (int k = 0; k < 4; ++k) rfc[k] = row4col[lane + 64 * k];
  }

  // ---- Per-batch loss partials (identical fp order to R1/R2/R4) ----
  double loc = 0.0, cpos = 0.0, cneg = 0.0;
#pragma unroll
  for (int k = 0; k < 4; ++k) {
    const int l = rfc[k];
    if (l >= 0) {
      const float d0 = __fsub_rn(px[k], lab_x[l]);
      const float d1 = __fsub_rn(py[k], lab_y[l]);
      const float d2 = __fsub_rn(pz[k], lab_z[l]);
      const float nd = __fadd_rn(__fadd_rn(__fmul_rn(d0, d0), __fmul_rn(d1, d1)),
                                 __fmul_rn(d2, d2));
      loc += (double)nd;
      cpos -= (double)lc[k];
    } else {
      cneg -= (double)lca[k];
    }
  }
  for (int off = 32; off >= 1; off >>= 1) {
    loc += __shfl_xor(loc, off, 64);
    cpos += __shfl_xor(cpos, off, 64);
    cneg += __shfl_xor(cneg, off, 64);
  }
  if (lane == 0) {
    ws[b * 3 + 0] = loc;   // sum of nd over matched pairs
    ws[b * 3 + 1] = cpos;  // -sum log_c over matched preds
    ws[b * 3 + 2] = cneg;  // -sum log_ca over unmatched preds
  }
}

__global__ __launch_bounds__(64) void reduce_kernel(
    const double* __restrict__ ws, float* __restrict__ out)
{
  const int lane = threadIdx.x;
  double loc = 0.0, conf = 0.0;
  for (int b = lane; b < B_; b += 64) {
    loc += ws[b * 3 + 0];
    conf += ws[b * 3 + 1] + ws[b * 3 + 2] + 1e-4;
  }
  for (int off = 32; off >= 1; off >>= 1) {
    loc += __shfl_xor(loc, off, 64);
    conf += __shfl_xor(conf, off, 64);
  }
  if (lane == 0) {
    const double location_loss = loc * 0.5;
    const double lloc = 0.1 * location_loss;          // ALPHA * location_loss
    out[0] = (float)(lloc + conf);                    // total loss
    out[1] = (float)lloc;                             // ALPHA * location_loss
    out[2] = (float)ws[(B_ - 1) * 3 + 1];             // conf_pos_b[-1]
    out[3] = (float)ws[(B_ - 1) * 3 + 2];             // conf_neg_b[-1]
  }
}

extern "C" void kernel_launch(void* const* d_in, const int* in_sizes, int n_in,
                              void* d_out, int out_size, void* d_ws, size_t ws_size,
                              hipStream_t stream) {
  const float* pred = (const float*)d_in[0];       // (B, N, 4) fp32
  const float* label = (const float*)d_in[1];      // (B, M, 3) fp32
  const int* label_len = (const int*)d_in[2];      // (B,) int32
  double* ws = (double*)d_ws;                      // B*3 doubles
  float* out = (float*)d_out;                      // 4 fp32 scalars

  lsa_loss_kernel<<<B_, 64, 0, stream>>>(pred, label, label_len, ws);
  reduce_kernel<<<1, 64, 0, stream>>>(ws, out);
}

// Round 6
// 209.426 us; speedup vs baseline: 9.9331x; 2.7289x over previous
//
#include <hip/hip_runtime.h>
#include <math.h>

// LineFinderLoss: B=384 independent exact LSAs (L x 256, L<=64) + loss.
// One wave per batch; each lane owns 4 pred columns (j = lane + 64k).
// Round 6: fully register-resident JV. vs R5 (bit-identical decisions):
//  - prev[] -> pv[4] registers (cndmask, no conditional LDS stores)
//  - shortest_lds eliminated: SR-row dual update needs shortest[col4row[r]],
//    which IS min_val at the pop that added row r -> lane r records mv_join.
//  - row4col/col4row -> rfc[4]/c4r registers; backtrack = readlane lockstep
//    (~35 cy/step vs ~250 cy of dependent LDS round-trips).
//  - zero barriers after init (single wave, wave-synchronous).

#define B_ 384
#define N_ 256
#define M_ 64

typedef unsigned long long u64;

static __device__ __forceinline__ double mkdbl(int lo, int hi) {
  return __longlong_as_double(((long long)hi << 32) | (unsigned int)lo);
}
static __device__ __forceinline__ int lo32d(double d) {
  return (int)__double_as_longlong(d);
}
static __device__ __forceinline__ int hi32d(double d) {
  return (int)(__double_as_longlong(d) >> 32);
}
static __device__ __forceinline__ float readlane_f32(float x, int l) {
  return __int_as_float(__builtin_amdgcn_readlane(__float_as_int(x), l));
}
static __device__ __forceinline__ double readlane_f64(double x, int l) {
  int lo = __builtin_amdgcn_readlane(lo32d(x), l);
  int hi = __builtin_amdgcn_readlane(hi32d(x), l);
  return mkdbl(lo, hi);
}

// fp32 cost with numpy's exact association order (bit-exact vs reference):
// C = ((0.1f*nd)*0.5f - lc) + lca, nd = (d0*d0 + d1*d1) + d2*d2
static __device__ __forceinline__ float costf(float px, float py, float pz,
                                              float lc, float lca,
                                              float lx, float ly, float lz) {
  const float d0 = __fsub_rn(px, lx);
  const float d1 = __fsub_rn(py, ly);
  const float d2 = __fsub_rn(pz, lz);
  const float nd = __fadd_rn(__fadd_rn(__fmul_rn(d0, d0), __fmul_rn(d1, d1)),
                             __fmul_rn(d2, d2));
  return __fadd_rn(__fsub_rn(__fmul_rn(__fmul_rn(0.1f, nd), 0.5f), lc), lca);
}

// f64 min-reduce step via DPP (keys finite, >= 0, payload in low byte).
// Lanes without a source get max-finite-double (lo=-1, hi=0x7FEFFFFF).
#define DPP_MIN_F64(CTRL, RMASK)                                               \
  {                                                                            \
    int nlo = __builtin_amdgcn_update_dpp(-1, lo32d(ck), CTRL, RMASK, 0xF, false);         \
    int nhi = __builtin_amdgcn_update_dpp(0x7FEFFFFF, hi32d(ck), CTRL, RMASK, 0xF, false); \
    ck = fmin(ck, mkdbl(nlo, nhi));                                            \
  }

__global__ __launch_bounds__(64) void lsa_loss_kernel(
    const float* __restrict__ pred,
    const float* __restrict__ label,
    const int* __restrict__ label_len,
    double* __restrict__ ws)
{
  const int b = blockIdx.x;
  const int lane = threadIdx.x;  // 0..63

  __shared__ float lab_x[M_], lab_y[M_], lab_z[M_];
  __shared__ int row4col_init[N_];
  __shared__ int claim[N_];     // greedy: min row index claiming column j
  __shared__ float4 colA[N_];   // {px, py, pz, lc} per column
  __shared__ float collca[N_];

  // Labels: lane r owns label row r (registers) + LDS copy for the epilogue.
  const float* lp = label + (size_t)(b * M_ + lane) * 3;
  const float labx = lp[0], laby = lp[1], labz = lp[2];
  lab_x[lane] = labx; lab_y[lane] = laby; lab_z[lane] = labz;

  // Per-lane column data.
  float px[4], py[4], pz[4], lc[4], lca[4];
  double v[4];
  const float4* pred4 = reinterpret_cast<const float4*>(pred);
#pragma unroll
  for (int k = 0; k < 4; ++k) {
    const int j = lane + 64 * k;
    const float4 p = pred4[b * N_ + j];
    px[k] = p.x; py[k] = p.y; pz[k] = p.z;
    lc[k]  = logf(__fadd_rn(p.w, 1e-5f));
    lca[k] = logf(__fadd_rn(__fsub_rn(1.0f, p.w), 1e-5f));
    v[k] = 0.0;
    row4col_init[j] = -1;
    claim[j] = 0x7FFFFFFF;
    colA[j] = make_float4(p.x, p.y, p.z, lc[k]);
    collca[j] = lca[k];
  }

  int L = label_len[b];
  L = (L < 1) ? 1 : ((L > M_) ? M_ : L);

  __syncthreads();

  // ---- VALID warm start: u_i = min_j C_ij (row reduction), v = 0 ----
  float uminf = INFINITY;
  int bj = 0;
#pragma unroll 4
  for (int j = 0; j < N_; ++j) {
    const float4 c4 = colA[j];     // broadcast (all lanes same addr)
    const float clca = collca[j];
    const float cf = costf(c4.x, c4.y, c4.z, c4.w, clca, labx, laby, labz);
    if (cf < uminf) { uminf = cf; bj = j; }  // strict <: first-index ties
  }
  double u_reg = (double)uminf;
  if (lane < L) atomicMin(&claim[bj], lane);
  __syncthreads();
  const bool won = (lane < L) && (claim[bj] == lane);
  int c4r = won ? bj : -1;              // col4row[lane], register-resident
  if (won) row4col_init[bj] = lane;
  u64 free_mask = __ballot((lane < L) && !won);
  __syncthreads();

  // row4col distributed in registers from here on (LDS never touched again).
  int rfc[4];
#pragma unroll
  for (int k = 0; k < 4; ++k) rfc[k] = row4col_init[lane + 64 * k];

  const double INF = (double)INFINITY;

  // ---- Augment free rows (ascending): exact shortest augmenting path ----
  while (free_mask) {
    const int cur_row = (int)__builtin_ctzll(free_mask);
    free_mask &= free_mask - 1;

    double shk[4] = {INF, INF, INF, INF};  // frozen keys (stop once SC)
    int pv[4] = {0, 0, 0, 0};              // prev row per owned column
    int schi[4] = {0, 0, 0, 0};            // SC flag per owned column
    double mv_join = 0.0;                  // min_val when this row joined SR
    int joined = 0;
    double min_val = 0.0;
    int i_cur = cur_row;
    double u_i = readlane_f64(u_reg, i_cur);
    float lx = readlane_f32(labx, i_cur);
    float ly = readlane_f32(laby, i_cur);
    float lz = readlane_f32(labz, i_cur);
    double t = 0.0 - u_i;  // t = min_val - u_i
    int sink = -1;

    while (true) {
      double tv[4];
#pragma unroll
      for (int k = 0; k < 4; ++k) tv[k] = t - v[k];

      double cand[4];
#pragma unroll
      for (int k = 0; k < 4; ++k) {
        const int j = lane + 64 * k;
        const float cf = costf(px[k], py[k], pz[k], lc[k], lca[k], lx, ly, lz);
        double dd = (double)cf + tv[k];
        dd = fmax(dd, 0.0);  // keys stay >= 0 (sign-safe ordering)
        const int klo = (lo32d(dd) & ~0xFF) | j;   // j in [0,255] == low byte
        const int khi = hi32d(dd);
        // SC mask: hi word -> 0x7FEFFFFF gives a huge FINITE value (no NaN).
        const int khi_m = schi[k] ? 0x7FEFFFFF : khi;
        const double c = mkdbl(klo, khi_m);
        const bool upd = c < shk[k];
        shk[k] = upd ? c : shk[k];       // branch-free, register-only
        pv[k]  = upd ? i_cur : pv[k];
        cand[k] = c;
      }
      // 2-level tree + 6 DPP steps, all v_min_f64.
      const double m01 = fmin(cand[0], cand[1]);
      const double m23 = fmin(cand[2], cand[3]);
      double ck = fmin(m01, m23);
      DPP_MIN_F64(0x111, 0xF);  // row_shr:1
      DPP_MIN_F64(0x112, 0xF);  // row_shr:2
      DPP_MIN_F64(0x114, 0xF);  // row_shr:4
      DPP_MIN_F64(0x118, 0xF);  // row_shr:8
      DPP_MIN_F64(0x142, 0xA);  // row_bcast:15 -> rows 1,3
      DPP_MIN_F64(0x143, 0xC);  // row_bcast:31 -> rows 2,3
      const int wlo = __builtin_amdgcn_readlane(lo32d(ck), 63);
      const int whi = __builtin_amdgcn_readlane(hi32d(ck), 63);
      const int j_min = wlo & 0xFF;
      min_val = mkdbl(wlo & ~0xFF, whi);
      const int kk = j_min >> 6;
      // Branch-free SC mark.
      const int hit = (lane == (j_min & 63)) ? 1 : 0;
      schi[0] |= hit & (int)(kk == 0);
      schi[1] |= hit & (int)(kk == 1);
      schi[2] |= hit & (int)(kk == 2);
      schi[3] |= hit & (int)(kk == 3);
      // row4col[j_min] from distributed registers.
      const int lsel = j_min & 63;
      const int r0 = __builtin_amdgcn_readlane(rfc[0], lsel);
      const int r1 = __builtin_amdgcn_readlane(rfc[1], lsel);
      const int r2 = __builtin_amdgcn_readlane(rfc[2], lsel);
      const int r3 = __builtin_amdgcn_readlane(rfc[3], lsel);
      const int r4 = (kk == 0) ? r0 : (kk == 1) ? r1 : (kk == 2) ? r2 : r3;
      if (r4 < 0) { sink = j_min; break; }
      i_cur = r4;
      // Lane i_cur joins SR: record min_val (== shortest[col4row[i_cur]]).
      if (lane == i_cur) { mv_join = min_val; joined = 1; }
      u_i = readlane_f64(u_reg, i_cur);
      lx = readlane_f32(labx, i_cur);
      ly = readlane_f32(laby, i_cur);
      lz = readlane_f32(labz, i_cur);
      t = min_val - u_i;
    }

    // Dual updates (pre-augmentation matching), reference fp order.
    if (lane == cur_row)  u_reg += min_val;
    else if (joined)      u_reg += min_val - mv_join;
#pragma unroll
    for (int k = 0; k < 4; ++k) {
      if (schi[k]) {
        const double shd = mkdbl(lo32d(shk[k]) & ~0xFF, hi32d(shk[k]));
        v[k] -= (min_val - shd);
      }
    }

    // Augment: lockstep walk over registers (uniform scalars via readlane).
    {
      int j = sink;
      while (true) {
        const int kkj = j >> 6, lj = j & 63;
        const int p0 = __builtin_amdgcn_readlane(pv[0], lj);
        const int p1 = __builtin_amdgcn_readlane(pv[1], lj);
        const int p2 = __builtin_amdgcn_readlane(pv[2], lj);
        const int p3 = __builtin_amdgcn_readlane(pv[3], lj);
        const int ii = (kkj == 0) ? p0 : (kkj == 1) ? p1 : (kkj == 2) ? p2 : p3;
        // row4col[j] = ii
        const bool self = (lane == lj);
        rfc[0] = (self && kkj == 0) ? ii : rfc[0];
        rfc[1] = (self && kkj == 1) ? ii : rfc[1];
        rfc[2] = (self && kkj == 2) ? ii : rfc[2];
        rfc[3] = (self && kkj == 3) ? ii : rfc[3];
        // col4row[ii], j = j, col4row[ii]
        const int jn = __builtin_amdgcn_readlane(c4r, ii);
        if (lane == ii) c4r = j;
        if (ii == cur_row) break;
        j = jn;
      }
    }
  }

  // ---- Per-batch loss partials (identical fp order to R1..R5) ----
  double loc = 0.0, cpos = 0.0, cneg = 0.0;
#pragma unroll
  for (int k = 0; k < 4; ++k) {
    const int l = rfc[k];
    if (l >= 0) {
      const float d0 = __fsub_rn(px[k], lab_x[l]);
      const float d1 = __fsub_rn(py[k], lab_y[l]);
      const float d2 = __fsub_rn(pz[k], lab_z[l]);
      const float nd = __fadd_rn(__fadd_rn(__fmul_rn(d0, d0), __fmul_rn(d1, d1)),
                                 __fmul_rn(d2, d2));
      loc += (double)nd;
      cpos -= (double)lc[k];
    } else {
      cneg -= (double)lca[k];
    }
  }
  for (int off = 32; off >= 1; off >>= 1) {
    loc += __shfl_xor(loc, off, 64);
    cpos += __shfl_xor(cpos, off, 64);
    cneg += __shfl_xor(cneg, off, 64);
  }
  if (lane == 0) {
    ws[b * 3 + 0] = loc;   // sum of nd over matched pairs
    ws[b * 3 + 1] = cpos;  // -sum log_c over matched preds
    ws[b * 3 + 2] = cneg;  // -sum log_ca over unmatched preds
  }
}

__global__ __launch_bounds__(64) void reduce_kernel(
    const double* __restrict__ ws, float* __restrict__ out)
{
  const int lane = threadIdx.x;
  double loc = 0.0, conf = 0.0;
  for (int b = lane; b < B_; b += 64) {
    loc += ws[b * 3 + 0];
    conf += ws[b * 3 + 1] + ws[b * 3 + 2] + 1e-4;
  }
  for (int off = 32; off >= 1; off >>= 1) {
    loc += __shfl_xor(loc, off, 64);
    conf += __shfl_xor(conf, off, 64);
  }
  if (lane == 0) {
    const double location_loss = loc * 0.5;
    const double lloc = 0.1 * location_loss;          // ALPHA * location_loss
    out[0] = (float)(lloc + conf);                    // total loss
    out[1] = (float)lloc;                             // ALPHA * location_loss
    out[2] = (float)ws[(B_ - 1) * 3 + 1];             // conf_pos_b[-1]
    out[3] = (float)ws[(B_ - 1) * 3 + 2];             // conf_neg_b[-1]
  }
}

extern "C" void kernel_launch(void* const* d_in, const int* in_sizes, int n_in,
                              void* d_out, int out_size, void* d_ws, size_t ws_size,
                              hipStream_t stream) {
  const float* pred = (const float*)d_in[0];       // (B, N, 4) fp32
  const float* label = (const float*)d_in[1];      // (B, M, 3) fp32
  const int* label_len = (const int*)d_in[2];      // (B,) int32
  double* ws = (double*)d_ws;                      // B*3 doubles
  float* out = (float*)d_out;                      // 4 fp32 scalars

  lsa_loss_kernel<<<B_, 64, 0, stream>>>(pred, label, label_len, ws);
  reduce_kernel<<<1, 64, 0, stream>>>(ws, out);
}